// Round 6
// baseline (4789.368 us; speedup 1.0000x reference)
//
#include <hip/hip_runtime.h>

// ============================================================================
// SelectionRNN on MI355X — round 6: round 5 + 8x h-replication.
// The h ping-pong region (128 KB) was read by all 256 WGs via sc0/sc1 (L3
// direct) => L3 bank contention on a tiny address window (~7.8 TB/s eff).
// Now writers publish h to 8 replicas spaced 256 KB apart; reader WG uses
// replica bid&7 => 8x address spread, ~32 readers per replica.
// Everything else identical to round 5.
// ============================================================================

typedef __bf16 bf16x8 __attribute__((ext_vector_type(8)));
typedef float f32x4 __attribute__((ext_vector_type(4)));

__device__ __forceinline__ unsigned short f2bf(float f) {
  unsigned u = __float_as_uint(f);
  u = u + 0x7FFFu + ((u >> 16) & 1u);   // RNE (inputs finite)
  return (unsigned short)(u >> 16);
}
__device__ __forceinline__ float sigm_(float x) { return 1.f / (1.f + __expf(-x)); }
__device__ __forceinline__ float tanh_(float x) { return 1.f - 2.f / (__expf(2.f * x) + 1.f); }

// ---------------------------------------------------------------------------
__global__ void cvt_kernel(const float* __restrict__ s, unsigned short* __restrict__ d, int n) {
  int i = (blockIdx.x * 256 + threadIdx.x) * 4;
  if (i < n) {
    float4 v = *reinterpret_cast<const float4*>(s + i);
    ushort4 o = make_ushort4(f2bf(v.x), f2bf(v.y), f2bf(v.z), f2bf(v.w));
    *reinterpret_cast<ushort4*>(d + i) = o;
  }
}

// ---------------------------------------------------------------------------
// prep: weighted hidden, state init, replica init, bias prep, barrier clear.
// grid 128 (l=blk>>6, b=blk&63) x 256.
// hXbuf layout: [replica(8) stride 131072][parity(2) stride 65536][b*1024+u]
// ---------------------------------------------------------------------------
__global__ __launch_bounds__(256) void prep_kernel(
    const float* __restrict__ clstm, const float* __restrict__ hidden,
    const float* __restrict__ cell, const int* __restrict__ lens,
    float* __restrict__ hstate, float* __restrict__ cstate,
    unsigned short* __restrict__ h0buf, unsigned short* __restrict__ h1buf,
    const float* __restrict__ bih0, const float* __restrict__ bhh0,
    const float* __restrict__ bih1, const float* __restrict__ bhh1,
    float* __restrict__ bias0, float* __restrict__ bias1p,
    unsigned* __restrict__ bar) {
  const int tid = threadIdx.x, blk = blockIdx.x;
  const int l = blk >> 6, b = blk & 63;
  const float* crow = clstm + b * 1024;
  const float* hrow = hidden + ((size_t)l * 64 + b) * 1024;
  float cmn = 3.4e38f, cmx = -3.4e38f, hmn = 3.4e38f, hmx = -3.4e38f;
  for (int i = tid; i < 1024; i += 256) {
    float c = crow[i], h = hrow[i];
    cmn = fminf(cmn, c); cmx = fmaxf(cmx, c);
    hmn = fminf(hmn, h); hmx = fmaxf(hmx, h);
  }
#pragma unroll
  for (int off = 32; off > 0; off >>= 1) {
    cmn = fminf(cmn, __shfl_xor(cmn, off));
    cmx = fmaxf(cmx, __shfl_xor(cmx, off));
    hmn = fminf(hmn, __shfl_xor(hmn, off));
    hmx = fmaxf(hmx, __shfl_xor(hmx, off));
  }
  __shared__ float red[4][4];
  int wv = tid >> 6;
  if ((tid & 63) == 0) { red[wv][0] = cmn; red[wv][1] = cmx; red[wv][2] = hmn; red[wv][3] = hmx; }
  __syncthreads();
  cmn = fminf(fminf(red[0][0], red[1][0]), fminf(red[2][0], red[3][0]));
  cmx = fmaxf(fmaxf(red[0][1], red[1][1]), fmaxf(red[2][1], red[3][1]));
  hmn = fminf(fminf(red[0][2], red[1][2]), fminf(red[2][2], red[3][2]));
  hmx = fmaxf(fmaxf(red[0][3], red[1][3]), fmaxf(red[2][3], red[3][3]));
  const float crange = cmx - cmn, hrange = hmx - hmn;
  const int len = lens[b];
  const size_t base = ((size_t)l * 64 + b) * 1024;
  for (int i = tid; i < 1024; i += 256) {
    float cv = crow[i], hv = hrow[i];
    float s = (crange > 0.f) ? (cv - cmn) / crange : cv;
    float s2 = (hrange > 0.f) ? (hmn + s * hrange) : s;
    float cc = (len == 0) ? cv : s2;
    float w = 0.5f * hv + 0.5f * cc;          // HIDDEN_WEIGHT = 0.5
    hstate[base + i] = w;
    cstate[base + i] = cell[base + i];
    unsigned short wb = f2bf(w);
    unsigned short* dst = (l == 0) ? h0buf : h1buf;
#pragma unroll
    for (int rep = 0; rep < 8; ++rep)
      dst[rep * 131072 + b * 1024 + i] = wb;   // parity 0
  }
  if (blk == 0) {
    for (int n = tid; n < 4096; n += 256) {
      bias0[n] = bih0[n] + bhh0[n];
      bias1p[(n & 1023) * 4 + (n >> 10)] = bih1[n] + bhh1[n];
    }
    bar[tid] = 0u; bar[256 + tid] = 0u;   // subs 0..240, gen 496, mirrors 256..368
  }
}

// ---------------------------------------------------------------------------
// bf16 MFMA GEMM, 128x128 tile. EPI 0 scatters into rec G2 layout.
// ---------------------------------------------------------------------------
template <int AMODE, int EPI>
__global__ __launch_bounds__(256) void gemm_kernel(
    const void* __restrict__ Ap, const unsigned short* __restrict__ Bw,
    void* __restrict__ Cout, const float* __restrict__ bias,
    const int* __restrict__ lens, int M, int N, int K, int t0) {
  __shared__ unsigned short Al[128][40];
  __shared__ unsigned short Bl[128][40];
  const int tid = threadIdx.x;
  const int m0 = blockIdx.y * 128, n0 = blockIdx.x * 128;
  const int srow = tid >> 2;
  const int c8 = (tid & 3) * 8;
  size_t aoff0, aoff1;
  {
    int r = m0 + srow, r2 = r + 64;
    if (AMODE == 0) {
      aoff0 = (size_t)r * K; aoff1 = (size_t)r2 * K;
    } else {
      aoff0 = ((size_t)(r & 63) * 256 + t0 + (r >> 6)) * K;
      aoff1 = ((size_t)(r2 & 63) * 256 + t0 + (r2 >> 6)) * K;
    }
  }
  const size_t boff0 = (size_t)(n0 + srow) * K, boff1 = (size_t)(n0 + srow + 64) * K;
  const int wave = tid >> 6, lane = tid & 63, ln = lane & 15, quad = lane >> 4;
  const int mq = (wave >> 1) * 64, nq = (wave & 1) * 64;
  f32x4 acc[4][4] = {};
  const int nkt = K >> 5;
  for (int kt = 0; kt < nkt; ++kt) {
    const int kc = kt * 32 + c8;
    if (AMODE == 1) {
      const float* A = (const float*)Ap;
      const float* p0 = A + aoff0 + kc;
      const float* p1 = A + aoff1 + kc;
      float4 v0 = *reinterpret_cast<const float4*>(p0);
      float4 v0b = *reinterpret_cast<const float4*>(p0 + 4);
      float4 v1 = *reinterpret_cast<const float4*>(p1);
      float4 v1b = *reinterpret_cast<const float4*>(p1 + 4);
      *reinterpret_cast<ushort4*>(&Al[srow][c8]) =
          make_ushort4(f2bf(v0.x), f2bf(v0.y), f2bf(v0.z), f2bf(v0.w));
      *reinterpret_cast<ushort4*>(&Al[srow][c8 + 4]) =
          make_ushort4(f2bf(v0b.x), f2bf(v0b.y), f2bf(v0b.z), f2bf(v0b.w));
      *reinterpret_cast<ushort4*>(&Al[srow + 64][c8]) =
          make_ushort4(f2bf(v1.x), f2bf(v1.y), f2bf(v1.z), f2bf(v1.w));
      *reinterpret_cast<ushort4*>(&Al[srow + 64][c8 + 4]) =
          make_ushort4(f2bf(v1b.x), f2bf(v1b.y), f2bf(v1b.z), f2bf(v1b.w));
    } else {
      const unsigned short* A = (const unsigned short*)Ap;
      *reinterpret_cast<int4*>(&Al[srow][c8]) = *reinterpret_cast<const int4*>(A + aoff0 + kc);
      *reinterpret_cast<int4*>(&Al[srow + 64][c8]) = *reinterpret_cast<const int4*>(A + aoff1 + kc);
    }
    *reinterpret_cast<int4*>(&Bl[srow][c8]) = *reinterpret_cast<const int4*>(Bw + boff0 + kc);
    *reinterpret_cast<int4*>(&Bl[srow + 64][c8]) = *reinterpret_cast<const int4*>(Bw + boff1 + kc);
    __syncthreads();
    bf16x8 af[4], bfr[4];
#pragma unroll
    for (int i = 0; i < 4; ++i) {
      af[i] = *reinterpret_cast<const bf16x8*>(&Al[mq + i * 16 + ln][quad * 8]);
      bfr[i] = *reinterpret_cast<const bf16x8*>(&Bl[nq + i * 16 + ln][quad * 8]);
    }
#pragma unroll
    for (int i = 0; i < 4; ++i)
#pragma unroll
      for (int j = 0; j < 4; ++j)
        acc[i][j] = __builtin_amdgcn_mfma_f32_16x16x32_bf16(af[i], bfr[j], acc[i][j], 0, 0, 0);
    __syncthreads();
  }
#pragma unroll
  for (int i = 0; i < 4; ++i) {
    int mmb = m0 + mq + i * 16 + quad * 4;
#pragma unroll
    for (int j = 0; j < 4; ++j) {
      int nn = n0 + nq + j * 16 + ln;
      float bv = bias[nn];
#pragma unroll
      for (int r = 0; r < 4; ++r) {
        int mm = mmb + r;
        float v = acc[i][j][r] + bv;
        if (EPI >= 1) v = fmaxf(v, 0.f);
        if (EPI == 2) {
          if (lens[mm >> 8] == 0) v = 0.f;
          ((float*)Cout)[(size_t)mm * N + nn] = v;
        } else if (EPI == 1) {
          ((unsigned short*)Cout)[(size_t)mm * N + nn] = f2bf(v);
        } else {
          size_t idx = ((size_t)mm * 128 + ((nn >> 3) & 127)) * 32 + (nn & 7) * 4 + (nn >> 10);
          ((float*)Cout)[idx] = v;
        }
      }
    }
  }
}

// ---------------------------------------------------------------------------
// Fused two-layer recurrent kernel. Grid MUST be 256 WGs x 512 threads.
// WGs 0..127  (L0): units 8g..8g+7, Whh0 in LDS, K=1024.
// WGs 128..255(L1): units 8g..8g+7, [Wih1|Whh1] in LDS, K=2048.
// Interval k (s=t0+k): L0 computes step s (k<64); L1 computes step s-1 (s>=1).
// h exchange: 8 replicas, 256KB apart; reader WG uses replica bid&7; all 512
// threads publish (thread = replica(tid>>6) x batch(tid&63), 4 dword stores).
// Barrier: 16 subs -> gen -> 8 mirror lines; tid0 polls; syncthreads fan-out.
// ---------------------------------------------------------------------------
#define HL(dst, off) \
  asm volatile("global_load_dwordx4 %0, %1, off offset:" off " sc0 sc1" \
               : "=v"(dst) : "v"(abase))

__global__ __launch_bounds__(512) void rec2_kernel(
    const unsigned short* __restrict__ whh0b,
    const unsigned short* __restrict__ wih1b,
    const unsigned short* __restrict__ whh1b,
    const float* __restrict__ G2,             // [64*64][128][32] L0 preacts
    const float* __restrict__ bias1p,         // [1024][4]
    unsigned short* __restrict__ h0buf,       // [8][2][64*1024] bf16 replicas
    unsigned short* __restrict__ h1buf,       // [8][2][64*1024] bf16 replicas
    float* __restrict__ hstate, float* __restrict__ cstate,
    unsigned short* __restrict__ h1out,       // [64][256][1024] bf16
    const int* __restrict__ lens, int t0, int nint, unsigned* __restrict__ bar) {
  __shared__ unsigned short wlds[32 * 2056];  // L0 uses stride 1032, L1 2056
  __shared__ float glds[2][64][36];
  __shared__ unsigned short hsh[64][8];
  const int tid = threadIdx.x;
  const int bid = blockIdx.x;
  const bool isL1 = bid >= 128;
  const int g = bid & 127;
  const int rrep = bid & 7;                   // read replica
  // ---- stage weights ----
  if (!isL1) {
    int row = tid >> 4;                       // 32 rows, 16 thr/row, 64 shorts ea
    int c0 = (tid & 15) * 64;
    int wrow = (row >> 3) * 1024 + g * 8 + (row & 7);
    const int4* src = reinterpret_cast<const int4*>(whh0b + (size_t)wrow * 1024 + c0);
    int4* dst = reinterpret_cast<int4*>(wlds + row * 1032 + c0);
#pragma unroll
    for (int j = 0; j < 8; ++j) dst[j] = src[j];
  } else {
    int row = tid >> 4;                       // 32 rows, 16 thr/row, 128 shorts ea
    int ci = tid & 15;
    int wrow = (row >> 3) * 1024 + g * 8 + (row & 7);
    const unsigned short* src = (ci < 8)
        ? wih1b + (size_t)wrow * 1024 + ci * 128
        : whh1b + (size_t)wrow * 1024 + (ci - 8) * 128;
    const int4* s4 = reinterpret_cast<const int4*>(src);
    int4* dst = reinterpret_cast<int4*>(wlds + row * 2056 + ci * 128);
#pragma unroll
    for (int j = 0; j < 16; ++j) dst[j] = s4[j];
  }
  // ---- owner state ----
  const int b = tid >> 3, ul = tid & 7, u = g * 8 + ul;
  const size_t sbase = (size_t)(isL1 ? 65536 : 0) + b * 1024 + u;
  float cm = cstate[sbase], hm = hstate[sbase];
  int l0v = lens[b];
  const int len = l0v < 1 ? 1 : l0v;
  float4 b1v = {0.f, 0.f, 0.f, 0.f};
  if (isL1) b1v = *reinterpret_cast<const float4*>(bias1p + u * 4);
  const int wave = tid >> 6, lane = tid & 63, ln = lane & 15, quad = lane >> 4;
  const int mt = wave & 3, kw = wave >> 2;
  int lenm = 1;
  if (isL1) { int lv = lens[mt * 16 + ln]; lenm = lv < 1 ? 1 : lv; }
  const bf16x8 z8 = {};
  // writer mapping: replica = tid>>6 (i.e. wave), batch = tid&63 (i.e. lane)
  const int wrep = wave, wbb = lane;
  __syncthreads();

  for (int k = 0; k < nint; ++k) {
    const int s = t0 + k;
    const bool act = isL1 ? (s >= 1) : (k < 64);
    if (act) {
      float4 pg;
      f32x4 acc0 = {0.f, 0.f, 0.f, 0.f}, acc1 = {0.f, 0.f, 0.f, 0.f};
      if (!isL1) {
        pg = *reinterpret_cast<const float4*>(
            G2 + (((size_t)(k * 64 + b)) * 128 + g) * 32 + ul * 4);
        const unsigned short* abase = h0buf + rrep * 131072 + (s & 1) * 65536 +
                                      (mt * 16 + ln) * 1024 + kw * 512 + quad * 8;
        bf16x8 hf[16];
        HL(hf[0], "0");    HL(hf[1], "64");   HL(hf[2], "128");  HL(hf[3], "192");
        HL(hf[4], "256");  HL(hf[5], "320");  HL(hf[6], "384");  HL(hf[7], "448");
        HL(hf[8], "512");  HL(hf[9], "576");  HL(hf[10], "640"); HL(hf[11], "704");
        HL(hf[12], "768"); HL(hf[13], "832"); HL(hf[14], "896"); HL(hf[15], "960");
        asm volatile("s_waitcnt vmcnt(0)" ::: "memory");
        const unsigned short* wr0 = wlds + ln * 1032 + kw * 512 + quad * 8;
        const unsigned short* wr1 = wlds + (16 + ln) * 1032 + kw * 512 + quad * 8;
#pragma unroll
        for (int kt = 0; kt < 16; ++kt) {
          bf16x8 b0 = *reinterpret_cast<const bf16x8*>(wr0 + kt * 32);
          bf16x8 b1 = *reinterpret_cast<const bf16x8*>(wr1 + kt * 32);
          acc0 = __builtin_amdgcn_mfma_f32_16x16x32_bf16(hf[kt], b0, acc0, 0, 0, 0);
          acc1 = __builtin_amdgcn_mfma_f32_16x16x32_bf16(hf[kt], b1, acc1, 0, 0, 0);
        }
      } else {
        pg = b1v;
        const int sl = s - 1;                 // L1 step
        const unsigned short* abase = (kw == 0)
            ? h0buf + rrep * 131072 + (s & 1) * 65536 + (mt * 16 + ln) * 1024 + quad * 8
            : h1buf + rrep * 131072 + (sl & 1) * 65536 + (mt * 16 + ln) * 1024 + quad * 8;
        bf16x8 hf[32];
        HL(hf[0], "0");     HL(hf[1], "64");    HL(hf[2], "128");   HL(hf[3], "192");
        HL(hf[4], "256");   HL(hf[5], "320");   HL(hf[6], "384");   HL(hf[7], "448");
        HL(hf[8], "512");   HL(hf[9], "576");   HL(hf[10], "640");  HL(hf[11], "704");
        HL(hf[12], "768");  HL(hf[13], "832");  HL(hf[14], "896");  HL(hf[15], "960");
        HL(hf[16], "1024"); HL(hf[17], "1088"); HL(hf[18], "1152"); HL(hf[19], "1216");
        HL(hf[20], "1280"); HL(hf[21], "1344"); HL(hf[22], "1408"); HL(hf[23], "1472");
        HL(hf[24], "1536"); HL(hf[25], "1600"); HL(hf[26], "1664"); HL(hf[27], "1728");
        HL(hf[28], "1792"); HL(hf[29], "1856"); HL(hf[30], "1920"); HL(hf[31], "1984");
        asm volatile("s_waitcnt vmcnt(0)" ::: "memory");
        if (kw == 0 && sl >= lenm) {          // padded step: inter-layer input = 0
#pragma unroll
          for (int i = 0; i < 32; ++i) hf[i] = z8;
        }
        const unsigned short* wr0 = wlds + ln * 2056 + kw * 1024 + quad * 8;
        const unsigned short* wr1 = wlds + (16 + ln) * 2056 + kw * 1024 + quad * 8;
#pragma unroll
        for (int kt = 0; kt < 32; ++kt) {
          bf16x8 b0 = *reinterpret_cast<const bf16x8*>(wr0 + kt * 32);
          bf16x8 b1 = *reinterpret_cast<const bf16x8*>(wr1 + kt * 32);
          acc0 = __builtin_amdgcn_mfma_f32_16x16x32_bf16(hf[kt], b0, acc0, 0, 0, 0);
          acc1 = __builtin_amdgcn_mfma_f32_16x16x32_bf16(hf[kt], b1, acc1, 0, 0, 0);
        }
      }
#pragma unroll
      for (int r = 0; r < 4; ++r) {
        glds[kw][mt * 16 + quad * 4 + r][ln] = acc0[r];
        glds[kw][mt * 16 + quad * 4 + r][16 + ln] = acc1[r];
      }
      __syncthreads();   // A
      {
        float pi  = glds[0][b][ul]      + glds[1][b][ul]      + pg.x;
        float pf  = glds[0][b][8 + ul]  + glds[1][b][8 + ul]  + pg.y;
        float pgg = glds[0][b][16 + ul] + glds[1][b][16 + ul] + pg.z;
        float po  = glds[0][b][24 + ul] + glds[1][b][24 + ul] + pg.w;
        float ig = sigm_(pi), fg = sigm_(pf), gv = tanh_(pgg), og = sigm_(po);
        float cn_ = fg * cm + ig * gv;
        float hn_ = og * tanh_(cn_);
        int t = isL1 ? (s - 1) : s;
        bool valid = t < len;
        if (valid) { cm = cn_; hm = hn_; }
        hsh[b][ul] = f2bf(hm);
        if (isL1)
          h1out[((size_t)b * 256 + t) * 1024 + u] = valid ? f2bf(hn_) : (unsigned short)0;
      }
      __syncthreads();   // B
      // ---- publish h to all 8 replicas (thread = replica x batch) ----
      {
        const unsigned* hv = reinterpret_cast<const unsigned*>(&hsh[wbb][0]);
        unsigned v0 = hv[0], v1 = hv[1], v2 = hv[2], v3 = hv[3];
        unsigned short* dptr = (isL1 ? h1buf + wrep * 131072 + (s & 1) * 65536
                                     : h0buf + wrep * 131072 + ((s + 1) & 1) * 65536)
                               + wbb * 1024 + g * 8;
        asm volatile("global_store_dword %0, %1, off sc0 sc1" :: "v"(dptr), "v"(v0) : "memory");
        asm volatile("global_store_dword %0, %1, off offset:4 sc0 sc1" :: "v"(dptr), "v"(v1) : "memory");
        asm volatile("global_store_dword %0, %1, off offset:8 sc0 sc1" :: "v"(dptr), "v"(v2) : "memory");
        asm volatile("global_store_dword %0, %1, off offset:12 sc0 sc1" :: "v"(dptr), "v"(v3) : "memory");
        asm volatile("s_waitcnt vmcnt(0)" ::: "memory");
      }
    }
    // ---- barrier: tid0 arrives, finisher fans out to 8 mirrors, tid0 polls
    //      its mirror, syncthreads broadcasts the release ----
    __syncthreads();
    if (tid == 0) {
      unsigned a = __hip_atomic_fetch_add(bar + ((bid & 15) << 4), 1u,
                                          __ATOMIC_RELAXED, __HIP_MEMORY_SCOPE_AGENT);
      if ((a & 15u) == 15u) {
        unsigned m = __hip_atomic_fetch_add(bar + 496, 1u,
                                            __ATOMIC_RELAXED, __HIP_MEMORY_SCOPE_AGENT);
        if ((m & 15u) == 15u) {
#pragma unroll
          for (int j = 0; j < 8; ++j)
            __hip_atomic_store(bar + 256 + (j << 4), m + 1u,
                               __ATOMIC_RELAXED, __HIP_MEMORY_SCOPE_AGENT);
        }
      }
      const unsigned tgt = 16u * (unsigned)(s + 1);
      while (__hip_atomic_load(bar + 256 + ((bid & 7) << 4),
                               __ATOMIC_RELAXED, __HIP_MEMORY_SCOPE_AGENT) < tgt)
        __builtin_amdgcn_s_sleep(2);
    }
    __syncthreads();
  }
  hstate[sbase] = hm;
  cstate[sbase] = cm;
}

// ---------------------------------------------------------------------------
__global__ void final_kernel(const float* __restrict__ hstate, const float* __restrict__ cstate,
                             const int* __restrict__ lens, float* __restrict__ out) {
  int i = blockIdx.x * 256 + threadIdx.x;   // [L][B][H]
  int b = (i >> 10) & 63;
  float z = (lens[b] == 0) ? 0.f : 1.f;
  out[4194304 + i] = z * hstate[i];
  out[4325376 + i] = z * cstate[i];
}

// ---------------------------------------------------------------------------
extern "C" void kernel_launch(void* const* d_in, const int* in_sizes, int n_in,
                              void* d_out, int out_size, void* d_ws, size_t ws_size,
                              hipStream_t stream) {
  const float* x = (const float*)d_in[0];
  const float* clstm = (const float*)d_in[1];
  const float* hidden = (const float*)d_in[2];
  const float* cell = (const float*)d_in[3];
  const int* lens = (const int*)d_in[4];
  const float* wih0 = (const float*)d_in[5];
  const float* whh0 = (const float*)d_in[6];
  const float* bih0 = (const float*)d_in[7];
  const float* bhh0 = (const float*)d_in[8];
  const float* wih1 = (const float*)d_in[9];
  const float* whh1 = (const float*)d_in[10];
  const float* bih1 = (const float*)d_in[11];
  const float* bhh1 = (const float*)d_in[12];
  const float* w1 = (const float*)d_in[13];
  const float* b1 = (const float*)d_in[14];
  const float* w2 = (const float*)d_in[15];
  const float* b2 = (const float*)d_in[16];
  float* out = (float*)d_out;

  char* ws = (char*)d_ws;
  size_t off = 0;
  auto alloc = [&](size_t bytes) -> void* {
    void* p = ws + off;
    off += (bytes + 255) & ~(size_t)255;
    return p;
  };
  unsigned short* wih0_b = (unsigned short*)alloc(2097152ull * 2);
  unsigned short* whh0_b = (unsigned short*)alloc(4194304ull * 2);
  unsigned short* wih1_b = (unsigned short*)alloc(4194304ull * 2);
  unsigned short* whh1_b = (unsigned short*)alloc(4194304ull * 2);
  unsigned short* w1_b = (unsigned short*)alloc(1048576ull * 2);
  unsigned short* w2_b = (unsigned short*)alloc(262144ull * 2);
  float* bias0 = (float*)alloc(4096 * 4);
  float* bias1p = (float*)alloc(4096 * 4);
  float* hstate = (float*)alloc(131072ull * 4);
  float* cstate = (float*)alloc(131072ull * 4);
  unsigned short* h0buf = (unsigned short*)alloc(1048576ull * 2);  // 8 replicas x 2 parity
  unsigned short* h1buf = (unsigned short*)alloc(1048576ull * 2);
  unsigned* bar = (unsigned*)alloc(2048);
  float* G = (float*)alloc(16777216ull * 4);          // G2 preacts / mlp hidden
  unsigned short* h1out = (unsigned short*)alloc(16777216ull * 2);

  cvt_kernel<<<2048, 256, 0, stream>>>(wih0, wih0_b, 2097152);
  cvt_kernel<<<4096, 256, 0, stream>>>(whh0, whh0_b, 4194304);
  cvt_kernel<<<4096, 256, 0, stream>>>(wih1, wih1_b, 4194304);
  cvt_kernel<<<4096, 256, 0, stream>>>(whh1, whh1_b, 4194304);
  cvt_kernel<<<1024, 256, 0, stream>>>(w1, w1_b, 1048576);
  cvt_kernel<<<256, 256, 0, stream>>>(w2, w2_b, 262144);

  prep_kernel<<<128, 256, 0, stream>>>(clstm, hidden, cell, lens, hstate, cstate,
                                       h0buf, h1buf, bih0, bhh0, bih1, bhh1,
                                       bias0, bias1p, bar);

  for (int c = 0; c < 4; ++c) {
    gemm_kernel<1, 0><<<dim3(32, 32), 256, 0, stream>>>(x, wih0_b, G, bias0, lens,
                                                        4096, 4096, 512, c * 64);
    rec2_kernel<<<256, 512, 0, stream>>>(whh0_b, wih1_b, whh1_b, G, bias1p,
                                         h0buf, h1buf, hstate, cstate, h1out, lens,
                                         c * 64, (c == 3) ? 65 : 64, bar);
  }
  // MLP head
  gemm_kernel<0, 1><<<dim3(8, 128), 256, 0, stream>>>(h1out, w1_b, (void*)G, b1, lens,
                                                      16384, 1024, 1024, 0);
  gemm_kernel<0, 2><<<dim3(2, 128), 256, 0, stream>>>((const void*)G, w2_b, out, b2, lens,
                                                      16384, 256, 1024, 0);
  final_kernel<<<512, 256, 0, stream>>>(hstate, cstate, lens, out);
}

// Round 7
// 2300.743 us; speedup vs baseline: 2.0817x; 2.0817x over previous
//
#include <hip/hip_runtime.h>

// ============================================================================
// SelectionRNN on MI355X — round 7: fragment-ordered h exchange.
// Round 6 lesson: sc0/sc1 stores write through to HBM (8x replicas => 1 GB
// writes => regression). Reverted to a single h copy. Round 5's real read
// cost: A-fragment loads had 2-KB lane stride => 64 sectors touched per load,
// 16/64 B used (4x amplification). New exchange layout stores h in MFMA
// fragment order: hX[mt(4)][kt(32)][quad(4)][ln(16)][j(8)] so each fragment
// load is 64 lanes x 16 B fully contiguous. Owner publishes stay 16-B/thread,
// now contiguous across 16 threads (full sectors).
// Everything else identical to round 5 (barrier, pipeline, GEMMs).
// ============================================================================

typedef __bf16 bf16x8 __attribute__((ext_vector_type(8)));
typedef float f32x4 __attribute__((ext_vector_type(4)));

__device__ __forceinline__ unsigned short f2bf(float f) {
  unsigned u = __float_as_uint(f);
  u = u + 0x7FFFu + ((u >> 16) & 1u);   // RNE (inputs finite)
  return (unsigned short)(u >> 16);
}
__device__ __forceinline__ float sigm_(float x) { return 1.f / (1.f + __expf(-x)); }
__device__ __forceinline__ float tanh_(float x) { return 1.f - 2.f / (__expf(2.f * x) + 1.f); }

// fragment-order element offset for h value of (batch b, unit u):
//   mt=b>>4, ln=b&15, kt=u>>5, quad=(u>>3)&3, j=u&7
//   off = mt*16384 + kt*512 + quad*128 + ln*8 + j
__device__ __forceinline__ int hxoff(int b, int u) {
  return (b >> 4) * 16384 + (u >> 5) * 512 + ((u >> 3) & 3) * 128 + (b & 15) * 8 + (u & 7);
}

// ---------------------------------------------------------------------------
__global__ void cvt_kernel(const float* __restrict__ s, unsigned short* __restrict__ d, int n) {
  int i = (blockIdx.x * 256 + threadIdx.x) * 4;
  if (i < n) {
    float4 v = *reinterpret_cast<const float4*>(s + i);
    ushort4 o = make_ushort4(f2bf(v.x), f2bf(v.y), f2bf(v.z), f2bf(v.w));
    *reinterpret_cast<ushort4*>(d + i) = o;
  }
}

// ---------------------------------------------------------------------------
// prep: weighted hidden, state init, hX parity-0 init (fragment order),
// bias prep, barrier clear. grid 128 (l=blk>>6, b=blk&63) x 256.
// hXbuf layout: [parity(2) stride 65536][fragment-order 65536]
// ---------------------------------------------------------------------------
__global__ __launch_bounds__(256) void prep_kernel(
    const float* __restrict__ clstm, const float* __restrict__ hidden,
    const float* __restrict__ cell, const int* __restrict__ lens,
    float* __restrict__ hstate, float* __restrict__ cstate,
    unsigned short* __restrict__ h0buf, unsigned short* __restrict__ h1buf,
    const float* __restrict__ bih0, const float* __restrict__ bhh0,
    const float* __restrict__ bih1, const float* __restrict__ bhh1,
    float* __restrict__ bias0, float* __restrict__ bias1p,
    unsigned* __restrict__ bar) {
  const int tid = threadIdx.x, blk = blockIdx.x;
  const int l = blk >> 6, b = blk & 63;
  const float* crow = clstm + b * 1024;
  const float* hrow = hidden + ((size_t)l * 64 + b) * 1024;
  float cmn = 3.4e38f, cmx = -3.4e38f, hmn = 3.4e38f, hmx = -3.4e38f;
  for (int i = tid; i < 1024; i += 256) {
    float c = crow[i], h = hrow[i];
    cmn = fminf(cmn, c); cmx = fmaxf(cmx, c);
    hmn = fminf(hmn, h); hmx = fmaxf(hmx, h);
  }
#pragma unroll
  for (int off = 32; off > 0; off >>= 1) {
    cmn = fminf(cmn, __shfl_xor(cmn, off));
    cmx = fmaxf(cmx, __shfl_xor(cmx, off));
    hmn = fminf(hmn, __shfl_xor(hmn, off));
    hmx = fmaxf(hmx, __shfl_xor(hmx, off));
  }
  __shared__ float red[4][4];
  int wv = tid >> 6;
  if ((tid & 63) == 0) { red[wv][0] = cmn; red[wv][1] = cmx; red[wv][2] = hmn; red[wv][3] = hmx; }
  __syncthreads();
  cmn = fminf(fminf(red[0][0], red[1][0]), fminf(red[2][0], red[3][0]));
  cmx = fmaxf(fmaxf(red[0][1], red[1][1]), fmaxf(red[2][1], red[3][1]));
  hmn = fminf(fminf(red[0][2], red[1][2]), fminf(red[2][2], red[3][2]));
  hmx = fmaxf(fmaxf(red[0][3], red[1][3]), fmaxf(red[2][3], red[3][3]));
  const float crange = cmx - cmn, hrange = hmx - hmn;
  const int len = lens[b];
  const size_t base = ((size_t)l * 64 + b) * 1024;
  unsigned short* dst = (l == 0) ? h0buf : h1buf;
  for (int i = tid; i < 1024; i += 256) {
    float cv = crow[i], hv = hrow[i];
    float s = (crange > 0.f) ? (cv - cmn) / crange : cv;
    float s2 = (hrange > 0.f) ? (hmn + s * hrange) : s;
    float cc = (len == 0) ? cv : s2;
    float w = 0.5f * hv + 0.5f * cc;          // HIDDEN_WEIGHT = 0.5
    hstate[base + i] = w;
    cstate[base + i] = cell[base + i];
    dst[hxoff(b, i)] = f2bf(w);               // parity 0, fragment order
  }
  if (blk == 0) {
    for (int n = tid; n < 4096; n += 256) {
      bias0[n] = bih0[n] + bhh0[n];
      bias1p[(n & 1023) * 4 + (n >> 10)] = bih1[n] + bhh1[n];
    }
    bar[tid] = 0u; bar[256 + tid] = 0u;   // subs 0..240, gen 496, mirrors 256..368
  }
}

// ---------------------------------------------------------------------------
// bf16 MFMA GEMM, 128x128 tile. EPI 0 scatters into rec G2 layout.
// ---------------------------------------------------------------------------
template <int AMODE, int EPI>
__global__ __launch_bounds__(256) void gemm_kernel(
    const void* __restrict__ Ap, const unsigned short* __restrict__ Bw,
    void* __restrict__ Cout, const float* __restrict__ bias,
    const int* __restrict__ lens, int M, int N, int K, int t0) {
  __shared__ unsigned short Al[128][40];
  __shared__ unsigned short Bl[128][40];
  const int tid = threadIdx.x;
  const int m0 = blockIdx.y * 128, n0 = blockIdx.x * 128;
  const int srow = tid >> 2;
  const int c8 = (tid & 3) * 8;
  size_t aoff0, aoff1;
  {
    int r = m0 + srow, r2 = r + 64;
    if (AMODE == 0) {
      aoff0 = (size_t)r * K; aoff1 = (size_t)r2 * K;
    } else {
      aoff0 = ((size_t)(r & 63) * 256 + t0 + (r >> 6)) * K;
      aoff1 = ((size_t)(r2 & 63) * 256 + t0 + (r2 >> 6)) * K;
    }
  }
  const size_t boff0 = (size_t)(n0 + srow) * K, boff1 = (size_t)(n0 + srow + 64) * K;
  const int wave = tid >> 6, lane = tid & 63, ln = lane & 15, quad = lane >> 4;
  const int mq = (wave >> 1) * 64, nq = (wave & 1) * 64;
  f32x4 acc[4][4] = {};
  const int nkt = K >> 5;
  for (int kt = 0; kt < nkt; ++kt) {
    const int kc = kt * 32 + c8;
    if (AMODE == 1) {
      const float* A = (const float*)Ap;
      const float* p0 = A + aoff0 + kc;
      const float* p1 = A + aoff1 + kc;
      float4 v0 = *reinterpret_cast<const float4*>(p0);
      float4 v0b = *reinterpret_cast<const float4*>(p0 + 4);
      float4 v1 = *reinterpret_cast<const float4*>(p1);
      float4 v1b = *reinterpret_cast<const float4*>(p1 + 4);
      *reinterpret_cast<ushort4*>(&Al[srow][c8]) =
          make_ushort4(f2bf(v0.x), f2bf(v0.y), f2bf(v0.z), f2bf(v0.w));
      *reinterpret_cast<ushort4*>(&Al[srow][c8 + 4]) =
          make_ushort4(f2bf(v0b.x), f2bf(v0b.y), f2bf(v0b.z), f2bf(v0b.w));
      *reinterpret_cast<ushort4*>(&Al[srow + 64][c8]) =
          make_ushort4(f2bf(v1.x), f2bf(v1.y), f2bf(v1.z), f2bf(v1.w));
      *reinterpret_cast<ushort4*>(&Al[srow + 64][c8 + 4]) =
          make_ushort4(f2bf(v1b.x), f2bf(v1b.y), f2bf(v1b.z), f2bf(v1b.w));
    } else {
      const unsigned short* A = (const unsigned short*)Ap;
      *reinterpret_cast<int4*>(&Al[srow][c8]) = *reinterpret_cast<const int4*>(A + aoff0 + kc);
      *reinterpret_cast<int4*>(&Al[srow + 64][c8]) = *reinterpret_cast<const int4*>(A + aoff1 + kc);
    }
    *reinterpret_cast<int4*>(&Bl[srow][c8]) = *reinterpret_cast<const int4*>(Bw + boff0 + kc);
    *reinterpret_cast<int4*>(&Bl[srow + 64][c8]) = *reinterpret_cast<const int4*>(Bw + boff1 + kc);
    __syncthreads();
    bf16x8 af[4], bfr[4];
#pragma unroll
    for (int i = 0; i < 4; ++i) {
      af[i] = *reinterpret_cast<const bf16x8*>(&Al[mq + i * 16 + ln][quad * 8]);
      bfr[i] = *reinterpret_cast<const bf16x8*>(&Bl[nq + i * 16 + ln][quad * 8]);
    }
#pragma unroll
    for (int i = 0; i < 4; ++i)
#pragma unroll
      for (int j = 0; j < 4; ++j)
        acc[i][j] = __builtin_amdgcn_mfma_f32_16x16x32_bf16(af[i], bfr[j], acc[i][j], 0, 0, 0);
    __syncthreads();
  }
#pragma unroll
  for (int i = 0; i < 4; ++i) {
    int mmb = m0 + mq + i * 16 + quad * 4;
#pragma unroll
    for (int j = 0; j < 4; ++j) {
      int nn = n0 + nq + j * 16 + ln;
      float bv = bias[nn];
#pragma unroll
      for (int r = 0; r < 4; ++r) {
        int mm = mmb + r;
        float v = acc[i][j][r] + bv;
        if (EPI >= 1) v = fmaxf(v, 0.f);
        if (EPI == 2) {
          if (lens[mm >> 8] == 0) v = 0.f;
          ((float*)Cout)[(size_t)mm * N + nn] = v;
        } else if (EPI == 1) {
          ((unsigned short*)Cout)[(size_t)mm * N + nn] = f2bf(v);
        } else {
          size_t idx = ((size_t)mm * 128 + ((nn >> 3) & 127)) * 32 + (nn & 7) * 4 + (nn >> 10);
          ((float*)Cout)[idx] = v;
        }
      }
    }
  }
}

// ---------------------------------------------------------------------------
// Fused two-layer recurrent kernel. Grid MUST be 256 WGs x 512 threads.
// WGs 0..127  (L0): units 8g..8g+7, Whh0 in LDS, K=1024.
// WGs 128..255(L1): units 8g..8g+7, [Wih1|Whh1] in LDS, K=2048.
// Interval k (s=t0+k): L0 computes step s (k<64); L1 computes step s-1 (s>=1).
// h exchange in fragment order: wave (kw,mt) lane L reads 16 B at
// base(mt,kt) + L*16 — fully coalesced 1-KB bursts, offsets kt*1024 B.
// Barrier: 16 subs -> gen -> 8 mirror lines; tid0 polls; syncthreads fan-out.
// ---------------------------------------------------------------------------
#define HLo(dst, ptr, off) \
  asm volatile("global_load_dwordx4 %0, %1, off offset:" off " sc0 sc1" \
               : "=v"(dst) : "v"(ptr))
#define HL4(h0, h1, h2, h3, ptr) \
  HLo(h0, ptr, "0"); HLo(h1, ptr, "1024"); HLo(h2, ptr, "2048"); HLo(h3, ptr, "3072")

__global__ __launch_bounds__(512) void rec2_kernel(
    const unsigned short* __restrict__ whh0b,
    const unsigned short* __restrict__ wih1b,
    const unsigned short* __restrict__ whh1b,
    const float* __restrict__ G2,             // [64*64][128][32] L0 preacts
    const float* __restrict__ bias1p,         // [1024][4]
    unsigned short* __restrict__ h0buf,       // [2][65536] bf16, fragment order
    unsigned short* __restrict__ h1buf,       // [2][65536] bf16, fragment order
    float* __restrict__ hstate, float* __restrict__ cstate,
    unsigned short* __restrict__ h1out,       // [64][256][1024] bf16
    const int* __restrict__ lens, int t0, int nint, unsigned* __restrict__ bar) {
  __shared__ unsigned short wlds[32 * 2056];  // L0 uses stride 1032, L1 2056
  __shared__ float glds[2][64][36];
  __shared__ unsigned short hsh[64][8];
  const int tid = threadIdx.x;
  const int bid = blockIdx.x;
  const bool isL1 = bid >= 128;
  const int g = bid & 127;
  // ---- stage weights ----
  if (!isL1) {
    int row = tid >> 4;                       // 32 rows, 16 thr/row, 64 shorts ea
    int c0 = (tid & 15) * 64;
    int wrow = (row >> 3) * 1024 + g * 8 + (row & 7);
    const int4* src = reinterpret_cast<const int4*>(whh0b + (size_t)wrow * 1024 + c0);
    int4* dst = reinterpret_cast<int4*>(wlds + row * 1032 + c0);
#pragma unroll
    for (int j = 0; j < 8; ++j) dst[j] = src[j];
  } else {
    int row = tid >> 4;                       // 32 rows, 16 thr/row, 128 shorts ea
    int ci = tid & 15;
    int wrow = (row >> 3) * 1024 + g * 8 + (row & 7);
    const unsigned short* src = (ci < 8)
        ? wih1b + (size_t)wrow * 1024 + ci * 128
        : whh1b + (size_t)wrow * 1024 + (ci - 8) * 128;
    const int4* s4 = reinterpret_cast<const int4*>(src);
    int4* dst = reinterpret_cast<int4*>(wlds + row * 2056 + ci * 128);
#pragma unroll
    for (int j = 0; j < 16; ++j) dst[j] = s4[j];
  }
  // ---- owner state ----
  const int b = tid >> 3, ul = tid & 7, u = g * 8 + ul;
  const size_t sbase = (size_t)(isL1 ? 65536 : 0) + b * 1024 + u;
  float cm = cstate[sbase], hm = hstate[sbase];
  int l0v = lens[b];
  const int len = l0v < 1 ? 1 : l0v;
  float4 b1v = {0.f, 0.f, 0.f, 0.f};
  if (isL1) b1v = *reinterpret_cast<const float4*>(bias1p + u * 4);
  const int wave = tid >> 6, lane = tid & 63, ln = lane & 15, quad = lane >> 4;
  const int mt = wave & 3, kw = wave >> 2;
  int lenm = 1;
  if (isL1) { int lv = lens[mt * 16 + ln]; lenm = lv < 1 ? 1 : lv; }
  const bf16x8 z8 = {};
  // publish address components (tid<64, b = tid):
  //   off = (tid>>4)*16384 + (g>>2)*512 + (g&3)*128 + (tid&15)*8
  const int puboff = (tid >> 4) * 16384 + (g >> 2) * 512 + (g & 3) * 128 + (tid & 15) * 8;
  __syncthreads();

  for (int k = 0; k < nint; ++k) {
    const int s = t0 + k;
    const bool act = isL1 ? (s >= 1) : (k < 64);
    if (act) {
      float4 pg;
      f32x4 acc0 = {0.f, 0.f, 0.f, 0.f}, acc1 = {0.f, 0.f, 0.f, 0.f};
      if (!isL1) {
        pg = *reinterpret_cast<const float4*>(
            G2 + (((size_t)(k * 64 + b)) * 128 + g) * 32 + ul * 4);
        // fragment-order coalesced reads: base(mt, kw) + lane*8 elems
        const unsigned short* p = h0buf + (s & 1) * 65536 +
                                  mt * 16384 + kw * 8192 + lane * 8;
        bf16x8 hf[16];
        HL4(hf[0], hf[1], hf[2], hf[3], p);
        HL4(hf[4], hf[5], hf[6], hf[7], p + 2048);
        HL4(hf[8], hf[9], hf[10], hf[11], p + 4096);
        HL4(hf[12], hf[13], hf[14], hf[15], p + 6144);
        asm volatile("s_waitcnt vmcnt(0)" ::: "memory");
        const unsigned short* wr0 = wlds + ln * 1032 + kw * 512 + quad * 8;
        const unsigned short* wr1 = wlds + (16 + ln) * 1032 + kw * 512 + quad * 8;
#pragma unroll
        for (int kt = 0; kt < 16; ++kt) {
          bf16x8 b0 = *reinterpret_cast<const bf16x8*>(wr0 + kt * 32);
          bf16x8 b1 = *reinterpret_cast<const bf16x8*>(wr1 + kt * 32);
          acc0 = __builtin_amdgcn_mfma_f32_16x16x32_bf16(hf[kt], b0, acc0, 0, 0, 0);
          acc1 = __builtin_amdgcn_mfma_f32_16x16x32_bf16(hf[kt], b1, acc1, 0, 0, 0);
        }
      } else {
        pg = b1v;
        const int sl = s - 1;                 // L1 step
        const unsigned short* p = (kw == 0)
            ? h0buf + (s & 1) * 65536 + mt * 16384 + lane * 8
            : h1buf + (sl & 1) * 65536 + mt * 16384 + lane * 8;
        bf16x8 hf[32];
        HL4(hf[0], hf[1], hf[2], hf[3], p);
        HL4(hf[4], hf[5], hf[6], hf[7], p + 2048);
        HL4(hf[8], hf[9], hf[10], hf[11], p + 4096);
        HL4(hf[12], hf[13], hf[14], hf[15], p + 6144);
        HL4(hf[16], hf[17], hf[18], hf[19], p + 8192);
        HL4(hf[20], hf[21], hf[22], hf[23], p + 10240);
        HL4(hf[24], hf[25], hf[26], hf[27], p + 12288);
        HL4(hf[28], hf[29], hf[30], hf[31], p + 14336);
        asm volatile("s_waitcnt vmcnt(0)" ::: "memory");
        if (kw == 0 && sl >= lenm) {          // padded step: inter-layer input = 0
#pragma unroll
          for (int i = 0; i < 32; ++i) hf[i] = z8;
        }
        const unsigned short* wr0 = wlds + ln * 2056 + kw * 1024 + quad * 8;
        const unsigned short* wr1 = wlds + (16 + ln) * 2056 + kw * 1024 + quad * 8;
#pragma unroll
        for (int kt = 0; kt < 32; ++kt) {
          bf16x8 b0 = *reinterpret_cast<const bf16x8*>(wr0 + kt * 32);
          bf16x8 b1 = *reinterpret_cast<const bf16x8*>(wr1 + kt * 32);
          acc0 = __builtin_amdgcn_mfma_f32_16x16x32_bf16(hf[kt], b0, acc0, 0, 0, 0);
          acc1 = __builtin_amdgcn_mfma_f32_16x16x32_bf16(hf[kt], b1, acc1, 0, 0, 0);
        }
      }
#pragma unroll
      for (int r = 0; r < 4; ++r) {
        glds[kw][mt * 16 + quad * 4 + r][ln] = acc0[r];
        glds[kw][mt * 16 + quad * 4 + r][16 + ln] = acc1[r];
      }
      __syncthreads();   // A
      {
        float pi  = glds[0][b][ul]      + glds[1][b][ul]      + pg.x;
        float pf  = glds[0][b][8 + ul]  + glds[1][b][8 + ul]  + pg.y;
        float pgg = glds[0][b][16 + ul] + glds[1][b][16 + ul] + pg.z;
        float po  = glds[0][b][24 + ul] + glds[1][b][24 + ul] + pg.w;
        float ig = sigm_(pi), fg = sigm_(pf), gv = tanh_(pgg), og = sigm_(po);
        float cn_ = fg * cm + ig * gv;
        float hn_ = og * tanh_(cn_);
        int t = isL1 ? (s - 1) : s;
        bool valid = t < len;
        if (valid) { cm = cn_; hm = hn_; }
        hsh[b][ul] = f2bf(hm);
        if (isL1)
          h1out[((size_t)b * 256 + t) * 1024 + u] = valid ? f2bf(hn_) : (unsigned short)0;
      }
      __syncthreads();   // B
      // ---- publish h (fragment-order, 16 B/thread contiguous per 16 thr) ----
      if (tid < 64) {
        const unsigned* hv = reinterpret_cast<const unsigned*>(&hsh[tid][0]);
        unsigned v0 = hv[0], v1 = hv[1], v2 = hv[2], v3 = hv[3];
        unsigned short* dptr = (isL1 ? h1buf + (s & 1) * 65536
                                     : h0buf + ((s + 1) & 1) * 65536) + puboff;
        asm volatile("global_store_dword %0, %1, off sc0 sc1" :: "v"(dptr), "v"(v0) : "memory");
        asm volatile("global_store_dword %0, %1, off offset:4 sc0 sc1" :: "v"(dptr), "v"(v1) : "memory");
        asm volatile("global_store_dword %0, %1, off offset:8 sc0 sc1" :: "v"(dptr), "v"(v2) : "memory");
        asm volatile("global_store_dword %0, %1, off offset:12 sc0 sc1" :: "v"(dptr), "v"(v3) : "memory");
        asm volatile("s_waitcnt vmcnt(0)" ::: "memory");
      }
    }
    // ---- barrier: tid0 arrives, finisher fans out to 8 mirrors, tid0 polls
    //      its mirror, syncthreads broadcasts the release ----
    __syncthreads();
    if (tid == 0) {
      unsigned a = __hip_atomic_fetch_add(bar + ((bid & 15) << 4), 1u,
                                          __ATOMIC_RELAXED, __HIP_MEMORY_SCOPE_AGENT);
      if ((a & 15u) == 15u) {
        unsigned m = __hip_atomic_fetch_add(bar + 496, 1u,
                                            __ATOMIC_RELAXED, __HIP_MEMORY_SCOPE_AGENT);
        if ((m & 15u) == 15u) {
#pragma unroll
          for (int j = 0; j < 8; ++j)
            __hip_atomic_store(bar + 256 + (j << 4), m + 1u,
                               __ATOMIC_RELAXED, __HIP_MEMORY_SCOPE_AGENT);
        }
      }
      const unsigned tgt = 16u * (unsigned)(s + 1);
      while (__hip_atomic_load(bar + 256 + ((bid & 7) << 4),
                               __ATOMIC_RELAXED, __HIP_MEMORY_SCOPE_AGENT) < tgt)
        __builtin_amdgcn_s_sleep(2);
    }
    __syncthreads();
  }
  hstate[sbase] = hm;
  cstate[sbase] = cm;
}

// ---------------------------------------------------------------------------
__global__ void final_kernel(const float* __restrict__ hstate, const float* __restrict__ cstate,
                             const int* __restrict__ lens, float* __restrict__ out) {
  int i = blockIdx.x * 256 + threadIdx.x;   // [L][B][H]
  int b = (i >> 10) & 63;
  float z = (lens[b] == 0) ? 0.f : 1.f;
  out[4194304 + i] = z * hstate[i];
  out[4325376 + i] = z * cstate[i];
}

// ---------------------------------------------------------------------------
extern "C" void kernel_launch(void* const* d_in, const int* in_sizes, int n_in,
                              void* d_out, int out_size, void* d_ws, size_t ws_size,
                              hipStream_t stream) {
  const float* x = (const float*)d_in[0];
  const float* clstm = (const float*)d_in[1];
  const float* hidden = (const float*)d_in[2];
  const float* cell = (const float*)d_in[3];
  const int* lens = (const int*)d_in[4];
  const float* wih0 = (const float*)d_in[5];
  const float* whh0 = (const float*)d_in[6];
  const float* bih0 = (const float*)d_in[7];
  const float* bhh0 = (const float*)d_in[8];
  const float* wih1 = (const float*)d_in[9];
  const float* whh1 = (const float*)d_in[10];
  const float* bih1 = (const float*)d_in[11];
  const float* bhh1 = (const float*)d_in[12];
  const float* w1 = (const float*)d_in[13];
  const float* b1 = (const float*)d_in[14];
  const float* w2 = (const float*)d_in[15];
  const float* b2 = (const float*)d_in[16];
  float* out = (float*)d_out;

  char* ws = (char*)d_ws;
  size_t off = 0;
  auto alloc = [&](size_t bytes) -> void* {
    void* p = ws + off;
    off += (bytes + 255) & ~(size_t)255;
    return p;
  };
  unsigned short* wih0_b = (unsigned short*)alloc(2097152ull * 2);
  unsigned short* whh0_b = (unsigned short*)alloc(4194304ull * 2);
  unsigned short* wih1_b = (unsigned short*)alloc(4194304ull * 2);
  unsigned short* whh1_b = (unsigned short*)alloc(4194304ull * 2);
  unsigned short* w1_b = (unsigned short*)alloc(1048576ull * 2);
  unsigned short* w2_b = (unsigned short*)alloc(262144ull * 2);
  float* bias0 = (float*)alloc(4096 * 4);
  float* bias1p = (float*)alloc(4096 * 4);
  float* hstate = (float*)alloc(131072ull * 4);
  float* cstate = (float*)alloc(131072ull * 4);
  unsigned short* h0buf = (unsigned short*)alloc(131072ull * 2);  // 2 parity x 65536
  unsigned short* h1buf = (unsigned short*)alloc(131072ull * 2);
  unsigned* bar = (unsigned*)alloc(2048);
  float* G = (float*)alloc(16777216ull * 4);          // G2 preacts / mlp hidden
  unsigned short* h1out = (unsigned short*)alloc(16777216ull * 2);

  cvt_kernel<<<2048, 256, 0, stream>>>(wih0, wih0_b, 2097152);
  cvt_kernel<<<4096, 256, 0, stream>>>(whh0, whh0_b, 4194304);
  cvt_kernel<<<4096, 256, 0, stream>>>(wih1, wih1_b, 4194304);
  cvt_kernel<<<4096, 256, 0, stream>>>(whh1, whh1_b, 4194304);
  cvt_kernel<<<1024, 256, 0, stream>>>(w1, w1_b, 1048576);
  cvt_kernel<<<256, 256, 0, stream>>>(w2, w2_b, 262144);

  prep_kernel<<<128, 256, 0, stream>>>(clstm, hidden, cell, lens, hstate, cstate,
                                       h0buf, h1buf, bih0, bhh0, bih1, bhh1,
                                       bias0, bias1p, bar);

  for (int c = 0; c < 4; ++c) {
    gemm_kernel<1, 0><<<dim3(32, 32), 256, 0, stream>>>(x, wih0_b, G, bias0, lens,
                                                        4096, 4096, 512, c * 64);
    rec2_kernel<<<256, 512, 0, stream>>>(whh0_b, wih1_b, whh1_b, G, bias1p,
                                         h0buf, h1buf, hstate, cstate, h1out, lens,
                                         c * 64, (c == 3) ? 65 : 64, bar);
  }
  // MLP head
  gemm_kernel<0, 1><<<dim3(8, 128), 256, 0, stream>>>(h1out, w1_b, (void*)G, b1, lens,
                                                      16384, 1024, 1024, 0);
  gemm_kernel<0, 2><<<dim3(2, 128), 256, 0, stream>>>((const void*)G, w2_b, out, b2, lens,
                                                      16384, 256, 1024, 0);
  final_kernel<<<512, 256, 0, stream>>>(hstate, cstate, lens, out);
}